// Round 7
// baseline (132.562 us; speedup 1.0000x reference)
//
#include <hip/hip_runtime.h>

// EVDLoRA loss: a[2048,4,256] f32 -> scalar.
// SINGLE fused kernel: reads f32 A directly, converts to bf16 while staging
// to LDS (reg-staged: global f32 -> v_cvt -> swizzled ds_write_b128), then
// S = A A^T via bf16 MFMA, K=256. bf16 rounding in S washes out in the
// 68M-term mean (validated r2-r6, absmax 0.0).
// Per (i,k,j): max over l, dp=exp(s-max);
//   i!=k: nsum += fmax(dp^2,1e-8) ; i==k: psum += dp over l!=j.
// loss = sum_blocks (C_NEG*nsum - C_POS*psum), one atomic per block.
// Structure: 8-wave blocks, TWO column-tiles per block sharing the A panel
// (waves 0-3 -> (bi,bkL), waves 4-7 -> (bi,bkR)); 1056 blocks, none empty.
// Double-buffered LDS (A,B1,B2 bf16 = 24 KB/buf); per iter: issue next-tile
// f32 loads early -> ds_read frags -> MFMA -> cvt+ds_write next tile -> barrier.

#define PD   8192
#define DDIM 256          // K in f32 elements
#define BM   128
#define BK   32           // K-cols per stage (= one 16x16x32 MFMA K-step)
#define NIT  (DDIM / BK)  // 8

typedef __bf16 bf16x8 __attribute__((ext_vector_type(8)));
typedef float f32x4 __attribute__((ext_vector_type(4)));

__device__ __forceinline__ int swz(int row) { return ((row >> 1) & 3) << 4; }

__device__ __forceinline__ bf16x8 pack8(float4 x, float4 y) {
    bf16x8 h;
    h[0] = (__bf16)x.x; h[1] = (__bf16)x.y; h[2] = (__bf16)x.z; h[3] = (__bf16)x.w;
    h[4] = (__bf16)y.x; h[5] = (__bf16)y.y; h[6] = (__bf16)y.z; h[7] = (__bf16)y.w;
    return h;
}

// max over the 4 lanes of a quad via DPP quad_perm
__device__ __forceinline__ float quadmax(float x) {
    int v = __builtin_amdgcn_mov_dpp(__builtin_bit_cast(int, x), 0xB1, 0xF, 0xF, true); // [1,0,3,2]
    float m = fmaxf(x, __builtin_bit_cast(float, v));
    v = __builtin_amdgcn_mov_dpp(__builtin_bit_cast(int, m), 0x4E, 0xF, 0xF, true);     // [2,3,0,1]
    return fmaxf(m, __builtin_bit_cast(float, v));
}

__global__ __launch_bounds__(512)
void evd_fused(const float* __restrict__ A, float* __restrict__ out)
{
    __shared__ __bf16 lds[2][3][BM * BK];   // [buf][A,B1,B2], 8 KB per slab
    __shared__ float wsum[8];

    // ---- block decode: 1056 blocks -> (bi, pair px); m204 bijective XCD swizzle ----
    const int nid = (blockIdx.z * gridDim.y + blockIdx.y) * gridDim.x + blockIdx.x;
    const int id  = (nid & 7) * 132 + (nid >> 3);        // 1056 = 8 * 132 exact
    const int xx  = id % 33;
    const int yzq = id / 33;
    const int yy  = yzq & 15;
    const int zz  = yzq >> 4;
    int rp, px;
    if (xx < 32 - yy) { rp = yy;      px = xx; }
    else              { rp = 31 - yy; px = xx - (32 - yy); }
    const int bi  = 2 * rp + zz;                          // row tile 0..63
    const int bkL = bi + 2 * px;
    int bkR = bkL + 1;
    const bool validR = (bkR < 64);
    if (!validR) bkR = bkL;                               // clip; waves 4-7 masked

    const int tid = threadIdx.x;
    const int lane = tid & 63, w = tid >> 6;              // 8 waves
    const int g = w >> 2;                                 // 0: tile L, 1: tile R
    const int sub = w & 3, wr = sub >> 1, wc = sub & 1;   // 2x2 within tile
    const int row0 = bi * BM;
    const int bk   = g ? bkR : bkL;
    const bool valid = g ? validR : true;

    // ---- staging assignment ----
    // A panel: 128 rows x 32 f32; thread -> (row=tid>>2, 8-f32 unit=tid&3)
    const int arow = tid >> 2, aunit = tid & 3;
    const float* gA = A + (size_t)(row0 + arow) * DDIM + aunit * 8;
    const int wA = arow * 64 + ((aunit * 16) ^ swz(arow));          // byte in A slab
    // B panels: each 256-thread half stages its own; thread -> (row=t2>>1, 2 units)
    const int t2 = tid & 255, brow = t2 >> 1;
    const int u0 = (t2 & 1) * 2, u1 = u0 + 1;
    const int colB = (tid < 256 ? bkL : bkR) * BM;
    const float* gB = A + (size_t)(colB + brow) * DDIM;
    const int bSlab = 8192 + (tid >= 256) * 8192;
    const int wB0 = bSlab + brow * 64 + ((u0 * 16) ^ swz(brow));
    const int wB1 = bSlab + brow * 64 + ((u1 * 16) ^ swz(brow));

    // ---- fragment read byte offsets (swizzled), loop-invariant ----
    const int fr = lane & 15, kq = lane >> 4;
    int aOff[4], bOff[4];
#pragma unroll
    for (int m = 0; m < 4; ++m) {
        const int ra = wr * 64 + m * 16 + fr;
        const int rb = wc * 64 + m * 16 + fr;
        aOff[m] = ra * 64 + ((kq * 16) ^ swz(ra));
        bOff[m] = 8192 + g * 8192 + rb * 64 + ((kq * 16) ^ swz(rb));
    }

    f32x4 acc[4][4];
#pragma unroll
    for (int m = 0; m < 4; ++m)
#pragma unroll
        for (int n = 0; n < 4; ++n)
#pragma unroll
            for (int q = 0; q < 4; ++q) acc[m][n][q] = 0.f;

    // staging registers (tile in flight)
    float4 ra0, ra1, rb0, rb1, rb2, rb3;
    auto issue = [&](int t) {
        const int kc = t * BK;
        ra0 = *(const float4*)(gA + kc);
        ra1 = *(const float4*)(gA + kc + 4);
        rb0 = *(const float4*)(gB + kc + u0 * 8);
        rb1 = *(const float4*)(gB + kc + u0 * 8 + 4);
        rb2 = *(const float4*)(gB + kc + u1 * 8);
        rb3 = *(const float4*)(gB + kc + u1 * 8 + 4);
    };
    auto cvtWrite = [&](int b) {
        char* base = (char*)&lds[b][0][0];
        *(bf16x8*)(base + wA)  = pack8(ra0, ra1);
        *(bf16x8*)(base + wB0) = pack8(rb0, rb1);
        *(bf16x8*)(base + wB1) = pack8(rb2, rb3);
    };

    // prologue: tile 0 staged to buf 0
    issue(0);
    cvtWrite(0);
    __syncthreads();

#pragma unroll
    for (int t = 0; t < NIT; ++t) {
        if (t + 1 < NIT) issue(t + 1);        // loads fly under ds_read + MFMA
        const char* base = (const char*)&lds[t & 1][0][0];
        bf16x8 af[4], bfr[4];
#pragma unroll
        for (int m = 0; m < 4; ++m) {
            af[m]  = *(const bf16x8*)(base + aOff[m]);
            bfr[m] = *(const bf16x8*)(base + bOff[m]);
        }
        __builtin_amdgcn_s_setprio(1);
#pragma unroll
        for (int m = 0; m < 4; ++m)
#pragma unroll
            for (int n = 0; n < 4; ++n)
                acc[m][n] = __builtin_amdgcn_mfma_f32_16x16x32_bf16(af[m], bfr[n], acc[m][n], 0, 0, 0);
        __builtin_amdgcn_s_setprio(0);
        if (t + 1 < NIT) {
            cvtWrite((t + 1) & 1);            // waits vmcnt via data dep
            __syncthreads();                  // tile t+1 visible; reads of buf[t&1] done
        }
    }

    // ---------------- fused epilogue ----------------
    // C/D layout: col = lane&15, row = (lane>>4)*4 + reg
    // Pre-scale y = 2*log2(e)*s: clamp-squares become exp2(y - ymax) directly.
    const float C_NEG = 1.0f / (2048.0f * 2047.0f * 16.0f);
    const float C_POS = 2.0f / (2048.0f * 12.0f);
    const float SCL = 2.0f * 1.4426950408889634f;
    const bool diag = (bi == bk);
    const bool ik = ((lane >> 4) == ((lane & 15) >> 2));
    float nsum = 0.f, psum = 0.f;

#pragma unroll
    for (int m = 0; m < 4; ++m) {
#pragma unroll
        for (int n = 0; n < 4; ++n) {
            float yv[4];
#pragma unroll
            for (int q = 0; q < 4; ++q) yv[q] = SCL * acc[m][n][q];
            const bool dfrag = diag && (wr == wc) && (m == n);
            // row-side: l-group = 4 lanes of a quad (cols)
#pragma unroll
            for (int r = 0; r < 4; ++r) {
                const float d2 = yv[r] - quadmax(yv[r]);     // = 2*log2e*(s-mm)
                if (dfrag) {
                    const float dp = __builtin_amdgcn_exp2f(0.5f * d2);  // exp(s-mm)
                    if (ik) {
                        if (r != (lane & 3)) psum += dp;                 // j != l
                    } else {
                        nsum += fmaxf(dp * dp, 1e-8f);
                    }
                } else {
                    nsum += fmaxf(__builtin_amdgcn_exp2f(d2), 1e-8f);
                }
            }
            // transposed side (off-diag tiles): l'-group = the 4 regs (rows)
            if (!diag) {
                const float ymax = fmaxf(fmaxf(fmaxf(yv[0], yv[1]), yv[2]), yv[3]);
#pragma unroll
                for (int r = 0; r < 4; ++r)
                    nsum += fmaxf(__builtin_amdgcn_exp2f(yv[r] - ymax), 1e-8f);
            }
        }
    }

    float contrib = valid ? (C_NEG * nsum - C_POS * psum) : 0.f;

    // block reduction -> one atomic per block
#pragma unroll
    for (int off = 32; off; off >>= 1) contrib += __shfl_down(contrib, off);
    if (lane == 0) wsum[w] = contrib;
    __syncthreads();
    if (tid == 0) {
        float s = 0.f;
#pragma unroll
        for (int i = 0; i < 8; ++i) s += wsum[i];
        atomicAdd(out, s);
    }
}

extern "C" void kernel_launch(void* const* d_in, const int* in_sizes, int n_in,
                              void* d_out, int out_size, void* d_ws, size_t ws_size,
                              hipStream_t stream) {
    const float* A = (const float*)d_in[0];
    float* out = (float*)d_out;
    hipMemsetAsync(out, 0, sizeof(float), stream);
    dim3 grid(33, 16, 2);                       // 1056 blocks = all tile-pairs
    evd_fused<<<grid, 512, 0, stream>>>(A, out);
}

// Round 8
// 97.157 us; speedup vs baseline: 1.3644x; 1.3644x over previous
//
#include <hip/hip_runtime.h>

// EVDLoRA loss: a[2048,4,256] f32 -> scalar.
// A = [8192][256] f32 -> W bf16 (cvt kernel, also zeroes out). S = A A^T via
// bf16 MFMA, K=256. (bf16 rounding in S washes out in the 68M-term mean;
// validated r2-r7, absmax 0.0.)
// Per (i,k,j): max over l, dp=exp(s-max);
//   i!=k: nsum += fmax(dp^2,1e-8) ; i==k: psum += dp over l!=j.
// loss = sum_blocks (C_NEG*nsum - C_POS*psum), one atomic per block.
// Round 8: BURST staging — stage a full K-half (A 32KB + B 32KB) in one shot,
// then 4 straight-line K-steps with NO barriers (compiler lgkmcnt scheduling).
// Only 3 barriers per block total (vs 16). 64KB LDS -> 2 blocks/CU overlap.
// Upper-triangle 128x128 tiles; off-diag tiles do both orientations.

#define PD   8192
#define KB   256          // K in bf16 elements
#define BM   128
#define KH   128          // K-half in bf16 elements (one 32KB slab per operand)

typedef __bf16 bf16x8 __attribute__((ext_vector_type(8)));
typedef float f32x4 __attribute__((ext_vector_type(4)));

__device__ __forceinline__ void gload16(const void* g, void* l) {
    __builtin_amdgcn_global_load_lds(
        (const __attribute__((address_space(1))) unsigned int*)g,
        (__attribute__((address_space(3))) unsigned int*)l, 16, 0, 0);
}

// max over the 4 lanes of a quad via DPP quad_perm
__device__ __forceinline__ float quadmax(float x) {
    int v = __builtin_amdgcn_mov_dpp(__builtin_bit_cast(int, x), 0xB1, 0xF, 0xF, true); // [1,0,3,2]
    float m = fmaxf(x, __builtin_bit_cast(float, v));
    v = __builtin_amdgcn_mov_dpp(__builtin_bit_cast(int, m), 0x4E, 0xF, 0xF, true);     // [2,3,0,1]
    return fmaxf(m, __builtin_bit_cast(float, v));
}

// ---------------- f32 -> bf16 conversion (+ out zero-init) ----------------
__global__ __launch_bounds__(256)
void cvt_bf16(const float* __restrict__ A, __bf16* __restrict__ W,
              float* __restrict__ out) {
    const int idx = blockIdx.x * 256 + threadIdx.x;      // 8 floats per thread
    if (idx == 0) *out = 0.f;                            // replaces memset dispatch
    const float4 v0 = reinterpret_cast<const float4*>(A)[idx * 2];
    const float4 v1 = reinterpret_cast<const float4*>(A)[idx * 2 + 1];
    bf16x8 h;
    h[0] = (__bf16)v0.x; h[1] = (__bf16)v0.y; h[2] = (__bf16)v0.z; h[3] = (__bf16)v0.w;
    h[4] = (__bf16)v1.x; h[5] = (__bf16)v1.y; h[6] = (__bf16)v1.z; h[7] = (__bf16)v1.w;
    *reinterpret_cast<bf16x8*>(W + (size_t)idx * 8) = h;
}

// ---------------- MFMA main kernel (burst-staged K-halves) ----------------
__global__ __launch_bounds__(256)
void evd_mfma(const __bf16* __restrict__ W, float* __restrict__ out)
{
    __shared__ __bf16 lds[2][BM * KH];   // [A,B] slabs, 32 KB each; row = 128 bf16 = 16 units of 16B
    __shared__ float wsum[4];

    // triangular decode with bijective XCD swizzle (2080 = 8 * 260)
    const int nid = blockIdx.y * 65 + blockIdx.x;
    const int id  = (nid & 7) * 260 + (nid >> 3);
    const int x = id % 65, y = id / 65;
    int bi, bk;
    if (x < 64 - y) { bi = y;      bk = y + x; }
    else            { bi = 63 - y; bk = x - 1; }

    const int tid = threadIdx.x;
    const int lane = tid & 63, wid = tid >> 6;
    const int wr = wid >> 1, wc = wid & 1;               // 2x2 waves, 64x64 each
    const int row0 = bi * BM, col0 = bk * BM;

    // ---- burst staging: per wave 8 A-instr + 8 B-instr per half ----
    // instr i writes LDS bytes [wid*8192 + i*1024 + lane*16): row = wid*32+i*4+(lane>>4),
    // unit = lane&15. Content swizzle LDS[row][u] = G[row][u ^ (row&15)] via source.
    const int srow = wid * 32 + (lane >> 4);
    const int sunit = lane & 15;
    const char* gW = (const char*)W;

    // ---- fragment read byte offsets: ra*256 + ((ks*4+kq)^fr)*16 ----
    const int fr = lane & 15, kq = lane >> 4;
    int aBase[4], bBase[4];
#pragma unroll
    for (int m = 0; m < 4; ++m) {
        aBase[m] = (wr * 64 + m * 16 + fr) * 256;
        bBase[m] = 32768 + (wc * 64 + m * 16 + fr) * 256;
    }

    f32x4 acc[4][4];
#pragma unroll
    for (int m = 0; m < 4; ++m)
#pragma unroll
        for (int n = 0; n < 4; ++n)
#pragma unroll
            for (int q = 0; q < 4; ++q) acc[m][n][q] = 0.f;

    // stage half h (16 gload16 per wave)
    auto stage = [&](int h) {
        const int hb = h * (KH * 2);                     // byte offset within W row
#pragma unroll
        for (int i = 0; i < 8; ++i) {
            const int r = srow + i * 4;
            const int gu = ((sunit ^ (r & 15)) * 16);
            gload16(gW + (size_t)(row0 + r) * (KB * 2) + hb + gu,
                    (char*)lds + wid * 8192 + i * 1024);
            gload16(gW + (size_t)(col0 + r) * (KB * 2) + hb + gu,
                    (char*)lds + 32768 + wid * 8192 + i * 1024);
        }
    };

    auto readFrags = [&](int ks, bf16x8* af, bf16x8* bfr) {
        const int u = ((ks * 4 + kq) ^ fr) * 16;
#pragma unroll
        for (int m = 0; m < 4; ++m) {
            af[m]  = *(const bf16x8*)((const char*)lds + aBase[m] + u);
            bfr[m] = *(const bf16x8*)((const char*)lds + bBase[m] + u);
        }
    };
    auto mfma16 = [&](const bf16x8* af, const bf16x8* bfr) {
        __builtin_amdgcn_s_setprio(1);
#pragma unroll
        for (int m = 0; m < 4; ++m)
#pragma unroll
            for (int n = 0; n < 4; ++n)
                acc[m][n] = __builtin_amdgcn_mfma_f32_16x16x32_bf16(af[m], bfr[n], acc[m][n], 0, 0, 0);
        __builtin_amdgcn_s_setprio(0);
    };

    // ---- half 0 ----
    stage(0);
    __syncthreads();                         // vmcnt(0): slab ready
    {
        bf16x8 af[4], bfr[4];
#pragma unroll
        for (int ks = 0; ks < 3; ++ks) {     // straight-line, no barriers
            readFrags(ks, af, bfr);
            mfma16(af, bfr);
        }
        readFrags(3, af, bfr);               // last frag reads of half 0
        __syncthreads();                     // lgkm drained: all waves done reading slab
        stage(1);                            // issue half-1 loads (fly under MFMAs)
        mfma16(af, bfr);
    }
    __syncthreads();                         // vmcnt(0): half-1 slab ready
    // ---- half 1 ----
    {
        bf16x8 af[4], bfr[4];
#pragma unroll
        for (int ks = 0; ks < 4; ++ks) {
            readFrags(ks, af, bfr);
            mfma16(af, bfr);
        }
    }

    // ---------------- fused epilogue ----------------
    // C/D layout: col = lane&15, row = (lane>>4)*4 + reg
    // Pre-scale y = 2*log2(e)*s: clamp-squares become exp2(y - ymax) directly.
    const float C_NEG = 1.0f / (2048.0f * 2047.0f * 16.0f);
    const float C_POS = 2.0f / (2048.0f * 12.0f);
    const float SCL = 2.0f * 1.4426950408889634f;
    const bool diag = (bi == bk);
    const bool ik = ((lane >> 4) == ((lane & 15) >> 2));
    float nsum = 0.f, psum = 0.f;

#pragma unroll
    for (int m = 0; m < 4; ++m) {
#pragma unroll
        for (int n = 0; n < 4; ++n) {
            float yv[4];
#pragma unroll
            for (int q = 0; q < 4; ++q) yv[q] = SCL * acc[m][n][q];
            const bool dfrag = diag && (wr == wc) && (m == n);
            // row-side: l-group = 4 lanes of a quad (cols)
#pragma unroll
            for (int r = 0; r < 4; ++r) {
                const float d2 = yv[r] - quadmax(yv[r]);     // = 2*log2e*(s-mm)
                if (dfrag) {
                    const float dp = __builtin_amdgcn_exp2f(0.5f * d2);  // exp(s-mm)
                    if (ik) {
                        if (r != (lane & 3)) psum += dp;                 // j != l
                    } else {
                        nsum += fmaxf(dp * dp, 1e-8f);
                    }
                } else {
                    nsum += fmaxf(__builtin_amdgcn_exp2f(d2), 1e-8f);
                }
            }
            // transposed side (off-diag tiles): l'-group = the 4 regs (rows)
            if (!diag) {
                const float ymax = fmaxf(fmaxf(fmaxf(yv[0], yv[1]), yv[2]), yv[3]);
#pragma unroll
                for (int r = 0; r < 4; ++r)
                    nsum += fmaxf(__builtin_amdgcn_exp2f(yv[r] - ymax), 1e-8f);
            }
        }
    }

    float contrib = C_NEG * nsum - C_POS * psum;

    // block reduction -> one atomic per block
#pragma unroll
    for (int off = 32; off; off >>= 1) contrib += __shfl_down(contrib, off);
    if ((tid & 63) == 0) wsum[tid >> 6] = contrib;
    __syncthreads();
    if (tid == 0) atomicAdd(out, wsum[0] + wsum[1] + wsum[2] + wsum[3]);
}

extern "C" void kernel_launch(void* const* d_in, const int* in_sizes, int n_in,
                              void* d_out, int out_size, void* d_ws, size_t ws_size,
                              hipStream_t stream) {
    const float* A = (const float*)d_in[0];
    float* out = (float*)d_out;
    __bf16* W = (__bf16*)d_ws;                 // 8192*256*2 = 4 MB scratch
    cvt_bf16<<<(PD * KB / 8) / 256, 256, 0, stream>>>(A, W, out);
    dim3 grid(65, 32);                          // exactly the 2080 upper-triangle tiles
    evd_mfma<<<grid, 256, 0, stream>>>(W, out);
}